// Round 10
// baseline (614.130 us; speedup 1.0000x reference)
//
#include <hip/hip_runtime.h>

// GCN 2-layer: N=200000, E=12800000, features 2 -> 16 -> 2.
// R2: rank trick -- aggregate only 2-dim vectors (before W1 / after W2).
// R4-R12: every agg variant with 3 divergent-address lane-ops/edge cost
//     7-10 cyc/edge/CU regardless of occupancy/locality/accumulator.
// R13 (CONFIRMED, 520us): per-edge cost = (# divergent lane-ops) x ~2cyc.
//     Full-dst sort (bucket sort + per-bucket LDS sub-sort) + wave-per-node
//     register aggregation cut agg to 1 op/edge: agg 150 -> <99us.
//     Pipeline op budget: hist 1 + scatter 2 + sortbins 3 + agg 1+1 = 8
//     ops/edge ~ 330us + BW/launches = 520 (model closes).
// R14: delete hist + both scans. Padded-bucket reservation: bucket b owns
//     [b*CAP, (b+1)*CAP) in sorted (CAP = mean+11sigma = 17792; overflow
//     P~1e-25, clamped = memory-safe). Scatter: local LDS hist (hist's
//     1 op/edge moves here), 1 global atomicAdd per (block,bucket) reserve
//     (1.6M total), local counting sort, clamped copy-out. sortbins emits
//     nodeStart AND nodeEnd (padding invalidates the cross-bucket sentinel);
//     deg = end-start. 8 kernels -> 6. ws 61.26MB < proven 61.61MB.

constexpr int N_NODES = 200000;
constexpr int N_EDGES = 12800000;
constexpr int RANGE_SHIFT = 8;                       // 256 nodes / bucket
constexpr int K_BUCKETS = (N_NODES + 255) / 256;     // 782
constexpr int SORT_BLOCKS = 2048;
constexpr int CHUNK = N_EDGES / SORT_BLOCKS;         // 6250 exactly
constexpr int CAP = 17792;                           // bucket capacity (mean 16368 + 11 sigma)
constexpr int CAPB = CAP;                            // sortbins LDS stage size

// ---------------- utility ----------------

__global__ __launch_bounds__(256) void zero_kernel(unsigned* __restrict__ p, int n) {
    int i = blockIdx.x * 256 + threadIdx.x;
    if (i < n) p[i] = 0u;
}

// ---------------- scatter: padded-bucket counting sort ----------------
// Per block: LDS hist over its 6250 edges -> global segment reservation via
// atomicAdd(gCur[b], cnt) -> LDS counting sort -> in-order copy-out into
// [b*CAP + reserved .. ) with clamp. Packed 4B entry:
// src (18b) | local_dst (8b) << 18.
__global__ __launch_bounds__(256) void scatter_kernel(const int* __restrict__ src,
                                                      const int* __restrict__ dst,
                                                      unsigned* __restrict__ gCur,
                                                      unsigned* __restrict__ sorted) {
    __shared__ unsigned h[K_BUCKETS];
    __shared__ unsigned s_cur[K_BUCKETS];
    __shared__ int      s_base[K_BUCKETS];
    __shared__ unsigned ssum[256];
    __shared__ unsigned ent[CHUNK];
    __shared__ unsigned short bk[CHUNK];

    int t = threadIdx.x;
    int base = blockIdx.x * CHUNK;
    for (int i = t; i < K_BUCKETS; i += 256) h[i] = 0;
    __syncthreads();

    // pass 1: local histogram (dst read; re-read in pass 2 is L1/L2-hot)
    for (int e = base + t; e < base + CHUNK; e += 256)
        atomicAdd(&h[((unsigned)dst[e]) >> RANGE_SHIFT], 1u);
    __syncthreads();

    // local exclusive prefix over 782 counts (4 per thread) + global reserve
    unsigned v[4], run = 0;
#pragma unroll
    for (int j = 0; j < 4; j++) {
        int idx = 4 * t + j;
        v[j] = (idx < K_BUCKETS) ? h[idx] : 0u;
    }
#pragma unroll
    for (int j = 0; j < 4; j++) { unsigned tmp = v[j]; v[j] = run; run += tmp; }
    ssum[t] = run;
    __syncthreads();
    for (int off = 1; off < 256; off <<= 1) {
        unsigned add = (t >= off) ? ssum[t - off] : 0u;
        __syncthreads();
        ssum[t] += add;
        __syncthreads();
    }
    unsigned excl = ssum[t] - run;
#pragma unroll
    for (int j = 0; j < 4; j++) {
        int idx = 4 * t + j;
        if (idx < K_BUCKETS) {
            unsigned cnt = (idx < K_BUCKETS) ? (((idx == 4 * t + j)) ? 0u : 0u) : 0u;
            (void)cnt;
            unsigned localStart = excl + v[j];
            unsigned c = h[idx];                       // this block's count
            unsigned old = c ? atomicAdd(&gCur[idx], c) : 0u;
            s_cur[idx]  = localStart;
            s_base[idx] = (int)((unsigned)idx * CAP + old) - (int)localStart;
        }
    }
    __syncthreads();

    // pass 2: place into LDS in bucket-sorted order
    for (int e = base + t; e < base + CHUNK; e += 256) {
        unsigned d = (unsigned)dst[e];
        unsigned s = (unsigned)src[e];
        unsigned b = d >> RANGE_SHIFT;
        unsigned lpos = atomicAdd(&s_cur[b], 1u);
        ent[lpos] = s | ((d & 255u) << 18);
        bk[lpos] = (unsigned short)b;
    }
    __syncthreads();

    // in-order coalesced copy-out, clamped to bucket capacity
    for (int i = t; i < CHUNK; i += 256) {
        unsigned b = bk[i];
        int pos = s_base[b] + i;
        if (pos < (int)((b + 1u) * CAP)) sorted[pos] = ent[i];
    }
}

// ---------------- per-bucket sub-sort by local dst ----------------
// One block per bucket; bucket data in [b*CAP, b*CAP + fill). Whole bucket
// staged into LDS before write-back (in-place safe). Emits nodeStart/nodeEnd.
__global__ __launch_bounds__(256) void sortbins_kernel(unsigned* __restrict__ sorted,
                                                       const unsigned* __restrict__ gCur,
                                                       unsigned* __restrict__ nodeStart,
                                                       unsigned* __restrict__ nodeEnd) {
    __shared__ unsigned ent[CAPB];
    __shared__ unsigned hist[256];
    __shared__ unsigned cur[256];
    __shared__ unsigned ssum[256];
    int t = threadIdx.x, b = blockIdx.x;
    int base = b * CAP;
    int n = (int)gCur[b];
    if (n > CAP) n = CAP;   // clamp (matches scatter's dropped writes)

    hist[t] = 0;
    __syncthreads();
    for (int i = t; i < n; i += 256) {
        unsigned w = sorted[base + i];
        ent[i] = w;
        atomicAdd(&hist[(w >> 18) & 255u], 1u);
    }
    __syncthreads();
    unsigned v = hist[t];
    ssum[t] = v;
    __syncthreads();
    for (int off = 1; off < 256; off <<= 1) {
        unsigned add = (t >= off) ? ssum[t - off] : 0u;
        __syncthreads();
        ssum[t] += add;
        __syncthreads();
    }
    unsigned excl = ssum[t] - v;
    cur[t] = excl;
    int node = (b << RANGE_SHIFT) + t;
    if (node < N_NODES) {
        nodeStart[node] = (unsigned)(base + (int)excl);
        nodeEnd[node]   = (unsigned)(base + (int)(excl + v));
    }
    __syncthreads();
    // place: scattered global writes confined to this bucket's ~70KB window
    for (int i = t; i < n; i += 256) {
        unsigned w = ent[i];
        unsigned p = atomicAdd(&cur[(w >> 18) & 255u], 1u);
        sorted[base + (int)p] = w;
    }
}

// ---------------- GCN phase ----------------

__global__ __launch_bounds__(256) void node1w_kernel(const float2* __restrict__ x,
                                                     const unsigned* __restrict__ nodeStart,
                                                     const unsigned* __restrict__ nodeEnd,
                                                     float* __restrict__ dinv,
                                                     float2* __restrict__ u) {
    int i = blockIdx.x * 256 + threadIdx.x;
    if (i >= N_NODES) return;
    unsigned deg = nodeEnd[i] - nodeStart[i] + 1u;  // +1 self loop
    float di = rsqrtf((float)deg);
    dinv[i] = di;
    float2 xi = x[i];
    u[i] = make_float2(di * xi.x, di * xi.y);
}

// Layer 1: one wave per node. Coalesced run read, divergent gather ONLY,
// register accumulate, butterfly reduce, fused 2->16->2 MLP epilogue.
__global__ __launch_bounds__(256) void aggw1_kernel(const unsigned* __restrict__ sorted,
                                                    const unsigned* __restrict__ nodeStart,
                                                    const unsigned* __restrict__ nodeEnd,
                                                    const float2* __restrict__ u,
                                                    const float* __restrict__ dinv,
                                                    const float* __restrict__ W1,
                                                    const float* __restrict__ b1,
                                                    const float* __restrict__ W2,
                                                    float2* __restrict__ g2) {
    int i = blockIdx.x * 4 + (threadIdx.x >> 6);
    if (i >= N_NODES) return;
    int lane = threadIdx.x & 63;
    int e0 = (int)nodeStart[i], e1 = (int)nodeEnd[i];
    float ax = 0.f, ay = 0.f;
    for (int k = e0 + lane; k < e1; k += 64) {
        unsigned w = sorted[k];
        float2 v = u[w & 0x3FFFFu];
        ax += v.x; ay += v.y;
    }
#pragma unroll
    for (int off = 32; off; off >>= 1) {
        ax += __shfl_xor(ax, off);
        ay += __shfl_xor(ay, off);
    }
    float di = dinv[i];
    float2 uu = u[i];
    float c0 = di * (ax + uu.x);
    float c1 = di * (ay + uu.y);
    float a0 = 0.f, a1 = 0.f;
    if (lane < 16) {
        float o = fmaxf(c0 * W1[lane] + c1 * W1[16 + lane] + b1[lane], 0.f);  // W1 (2,16)
        a0 = o * W2[2 * lane];                                                // W2 (16,2)
        a1 = o * W2[2 * lane + 1];
    }
#pragma unroll
    for (int off = 8; off; off >>= 1) {
        a0 += __shfl_xor(a0, off);
        a1 += __shfl_xor(a1, off);
    }
    if (lane == 0) g2[i] = make_float2(di * a0, di * a1);
}

// Layer 2: same core over table=g2; bias epilogue.
__global__ __launch_bounds__(256) void aggw2_kernel(const unsigned* __restrict__ sorted,
                                                    const unsigned* __restrict__ nodeStart,
                                                    const unsigned* __restrict__ nodeEnd,
                                                    const float2* __restrict__ g2,
                                                    const float* __restrict__ dinv,
                                                    const float* __restrict__ b2,
                                                    float2* __restrict__ out) {
    int i = blockIdx.x * 4 + (threadIdx.x >> 6);
    if (i >= N_NODES) return;
    int lane = threadIdx.x & 63;
    int e0 = (int)nodeStart[i], e1 = (int)nodeEnd[i];
    float ax = 0.f, ay = 0.f;
    for (int k = e0 + lane; k < e1; k += 64) {
        unsigned w = sorted[k];
        float2 v = g2[w & 0x3FFFFu];
        ax += v.x; ay += v.y;
    }
#pragma unroll
    for (int off = 32; off; off >>= 1) {
        ax += __shfl_xor(ax, off);
        ay += __shfl_xor(ay, off);
    }
    if (lane == 0) {
        float di = dinv[i];
        float2 g = g2[i];
        out[i] = make_float2(di * (ax + g.x) + b2[0],
                             di * (ay + g.y) + b2[1]);
    }
}

// ---------------- fallback path (R2-style, needs only 8 MB ws) ----------------

__global__ __launch_bounds__(256) void fb_deg(const int* __restrict__ dst, int* __restrict__ degi) {
    int e = blockIdx.x * 256 + threadIdx.x;
    if (e < N_EDGES) atomicAdd(&degi[dst[e]], 1);
}
__global__ __launch_bounds__(256) void fb_node1(const float* __restrict__ x, const int* __restrict__ degi,
                                                float* __restrict__ dinv, float2* __restrict__ u) {
    int i = blockIdx.x * 256 + threadIdx.x;
    if (i >= N_NODES) return;
    float di = rsqrtf((float)(degi[i] + 1));
    dinv[i] = di;
    float2 xi = ((const float2*)x)[i];
    u[i] = make_float2(di * xi.x, di * xi.y);
}
__global__ __launch_bounds__(256) void fb_agg(const int* __restrict__ src, const int* __restrict__ dst,
                                              const float2* __restrict__ table, float* __restrict__ acc) {
    int e = blockIdx.x * 256 + threadIdx.x;
    if (e >= N_EDGES) return;
    float2 v = table[src[e]];
    size_t d = dst[e];
    unsafeAtomicAdd(&acc[2 * d], v.x);
    unsafeAtomicAdd(&acc[2 * d + 1], v.y);
}
__global__ __launch_bounds__(256) void fb_node2(const float2* __restrict__ u, const float2* __restrict__ A1,
                                                const float* __restrict__ W1, const float* __restrict__ b1,
                                                const float* __restrict__ W2, const float* __restrict__ dinv,
                                                float2* __restrict__ g2) {
    int i = blockIdx.x * 256 + threadIdx.x;
    if (i >= N_NODES) return;
    float di = dinv[i];
    float2 a = A1[i], uu = u[i];
    float c0 = di * (a.x + uu.x), c1 = di * (a.y + uu.y);
    float a0 = 0.f, a1 = 0.f;
#pragma unroll
    for (int f = 0; f < 16; f++) {
        float o = fmaxf(c0 * W1[f] + c1 * W1[16 + f] + b1[f], 0.f);
        a0 += o * W2[2 * f];
        a1 += o * W2[2 * f + 1];
    }
    g2[i] = make_float2(di * a0, di * a1);
}
__global__ __launch_bounds__(256) void fb_node3(const float2* __restrict__ g2, const float2* __restrict__ A2,
                                                const float* __restrict__ b2, const float* __restrict__ dinv,
                                                float2* __restrict__ out) {
    int i = blockIdx.x * 256 + threadIdx.x;
    if (i >= N_NODES) return;
    float di = dinv[i];
    float2 a = A2[i], g = g2[i];
    out[i] = make_float2(di * (a.x + g.x) + b2[0], di * (a.y + g.y) + b2[1]);
}

// ---------------- launcher ----------------

extern "C" void kernel_launch(void* const* d_in, const int* in_sizes, int n_in,
                              void* d_out, int out_size, void* d_ws, size_t ws_size,
                              hipStream_t stream) {
    const float* x  = (const float*)d_in[0];
    const float* W1 = (const float*)d_in[1];
    const float* b1 = (const float*)d_in[2];
    const float* W2 = (const float*)d_in[3];
    const float* b2 = (const float*)d_in[4];
    const int* ei   = (const int*)d_in[5];   // (2,E): row 0 = src, row 1 = dst
    const int* src = ei;
    const int* dst = ei + N_EDGES;
    float2* out = (float2*)d_out;

    // ws layout (4B words), total 61.26 MB (< R8-proven 61.61 MB):
    //   sorted [K_BUCKETS*CAP = 13,913,344]   padded bucket regions
    //   nodeStart [200,000]
    //   nodeEnd   [200,000]
    //   dinv      [200,000]
    //   u         [400,000]
    //   g2        [400,000]
    //   gCur      [782 + pad]
    const size_t SORTED_W = (size_t)K_BUCKETS * CAP;   // 13,913,344
    const size_t need = (SORTED_W + 1400000 + 800) * 4;

    if (ws_size >= need) {
        unsigned* sorted    = (unsigned*)d_ws;
        unsigned* nodeStart = sorted + SORTED_W;
        unsigned* nodeEnd   = nodeStart + 200000;
        float*    dinv      = (float*)(nodeEnd + 200000);
        float2*   u         = (float2*)(dinv + 200000);
        float2*   g2        = u + 200000;
        unsigned* gCur      = (unsigned*)(g2 + 200000);

        zero_kernel<<<(K_BUCKETS + 255) / 256, 256, 0, stream>>>(gCur, K_BUCKETS);
        scatter_kernel<<<SORT_BLOCKS, 256, 0, stream>>>(src, dst, gCur, sorted);
        sortbins_kernel<<<K_BUCKETS, 256, 0, stream>>>(sorted, gCur, nodeStart, nodeEnd);
        node1w_kernel<<<K_BUCKETS, 256, 0, stream>>>((const float2*)x, nodeStart, nodeEnd,
                                                     dinv, u);
        aggw1_kernel<<<(N_NODES + 3) / 4, 256, 0, stream>>>(sorted, nodeStart, nodeEnd, u,
                                                            dinv, W1, b1, W2, g2);
        aggw2_kernel<<<(N_NODES + 3) / 4, 256, 0, stream>>>(sorted, nodeStart, nodeEnd, g2,
                                                            dinv, b2, out);
    } else {
        // R2-style fallback (8 MB ws): global atomics, ~3.1 ms.
        float* ws = (float*)d_ws;
        int*   degi = (int*)ws;
        float* A1   = ws + N_NODES;
        float* A2   = A1 + 2 * (size_t)N_NODES;
        float* dinvF = A2 + 2 * (size_t)N_NODES;
        float2* uF  = (float2*)(dinvF + N_NODES);
        float2* g2F = uF + N_NODES;
        constexpr int EB = (N_EDGES + 255) / 256;
        constexpr int NB = (N_NODES + 255) / 256;
        (void)hipMemsetAsync(degi, 0, 5 * (size_t)N_NODES * sizeof(float), stream);
        fb_deg<<<EB, 256, 0, stream>>>(dst, degi);
        fb_node1<<<NB, 256, 0, stream>>>(x, degi, dinvF, uF);
        fb_agg<<<EB, 256, 0, stream>>>(src, dst, uF, A1);
        fb_node2<<<NB, 256, 0, stream>>>(uF, (const float2*)A1, W1, b1, W2, dinvF, g2F);
        fb_agg<<<EB, 256, 0, stream>>>(src, dst, g2F, A2);
        fb_node3<<<NB, 256, 0, stream>>>(g2F, (const float2*)A2, b2, dinvF, out);
    }
}

// Round 11
// 507.617 us; speedup vs baseline: 1.2098x; 1.2098x over previous
//
#include <hip/hip_runtime.h>

// GCN 2-layer: N=200000, E=12800000, features 2 -> 16 -> 2.
// R2: rank trick -- aggregate only 2-dim vectors (before W1 / after W2).
// R4-R12: every agg variant with 3 divergent-address lane-ops/edge cost
//     7-10 cyc/edge/CU regardless of occupancy/locality/accumulator.
// R13 (CONFIRMED, 520us): per-edge cost = (# divergent lane-ops) x ~2cyc
//     (LDS/L1 class). Full-dst sort + wave-per-node register aggregation.
// R14 (FAILED, 614us): fusing hist into scatter did NOT amortize -- ops are
//     additive wherever they live; scatter also re-read dst + 1.6M contended
//     global atomics + padded-layout write-amp. Separation is correct.
// R15: R13 base + two surgical cuts:
//     (a) sortbins v2 -- placement via divergent LDS write + COALESCED
//         global write-out (was: scattered global write, ~4-7cyc + 35MB
//         write-amp). Pass 1 hist-only, pass 2 re-read L2-hot.
//     (b) node1w fused into sortbins (thread t holds its node's degree).
//     7 kernels.

constexpr int N_NODES = 200000;
constexpr int N_EDGES = 12800000;
constexpr int RANGE_SHIFT = 8;                       // 256 nodes / bucket
constexpr int K_BUCKETS = (N_NODES + 255) / 256;     // 782
constexpr int SORT_BLOCKS = 2048;
constexpr int CHUNK = N_EDGES / SORT_BLOCKS;         // 6250 exactly
constexpr int SCAN_R = SORT_BLOCKS / 256;            // 8
constexpr int CAPB = 18432;                          // bucket cap: mean 16368 + 16 sigma

// ---------------- sort phase A (verbatim R13, proven) ----------------

__global__ __launch_bounds__(256) void hist_kernel(const int* __restrict__ dst,
                                                   unsigned* __restrict__ blockHist) {
    __shared__ unsigned h[K_BUCKETS];
    for (int i = threadIdx.x; i < K_BUCKETS; i += 256) h[i] = 0;
    __syncthreads();
    int base = blockIdx.x * CHUNK;
    for (int e = base + threadIdx.x; e < base + CHUNK; e += 256)
        atomicAdd(&h[((unsigned)dst[e]) >> RANGE_SHIFT], 1u);
    __syncthreads();
    unsigned* row = blockHist + (size_t)blockIdx.x * K_BUCKETS;
    for (int i = threadIdx.x; i < K_BUCKETS; i += 256) row[i] = h[i];
}

__global__ __launch_bounds__(256) void scan_perblock_kernel(unsigned* __restrict__ blockHist,
                                                            unsigned* __restrict__ bucketTotal) {
    int b = blockIdx.x, t = threadIdx.x;
    unsigned v[SCAN_R], run = 0;
#pragma unroll
    for (int j = 0; j < SCAN_R; j++) v[j] = blockHist[(size_t)(SCAN_R * t + j) * K_BUCKETS + b];
#pragma unroll
    for (int j = 0; j < SCAN_R; j++) { unsigned tmp = v[j]; v[j] = run; run += tmp; }
    __shared__ unsigned sh[256];
    sh[t] = run;
    __syncthreads();
    for (int off = 1; off < 256; off <<= 1) {
        unsigned add = (t >= off) ? sh[t - off] : 0u;
        __syncthreads();
        sh[t] += add;
        __syncthreads();
    }
    unsigned excl = sh[t] - run;
#pragma unroll
    for (int j = 0; j < SCAN_R; j++)
        blockHist[(size_t)(SCAN_R * t + j) * K_BUCKETS + b] = excl + v[j];
    if (t == 255) bucketTotal[b] = sh[255];
}

__global__ __launch_bounds__(1024) void scan_buckets_kernel(const unsigned* __restrict__ bucketTotal,
                                                            unsigned* __restrict__ bucketStart) {
    __shared__ unsigned sh[1024];
    int t = threadIdx.x;
    unsigned v = (t < K_BUCKETS) ? bucketTotal[t] : 0u;
    sh[t] = v;
    __syncthreads();
    for (int off = 1; off < 1024; off <<= 1) {
        unsigned add = (t >= off) ? sh[t - off] : 0u;
        __syncthreads();
        sh[t] += add;
        __syncthreads();
    }
    if (t < K_BUCKETS) bucketStart[t] = sh[t] - v;
    if (t == K_BUCKETS - 1) bucketStart[K_BUCKETS] = sh[t];
}

// Block-local counting sort in LDS, in-order coalesced copy-out. Packed 4B
// entry: src (18b) | local_dst (8b) << 18. Per-block counts reconstructed
// from scanned blockHist rows (R8 trick).
__global__ __launch_bounds__(256) void scatter_kernel(const int* __restrict__ src,
                                                      const int* __restrict__ dst,
                                                      const unsigned* __restrict__ blockHist,
                                                      const unsigned* __restrict__ bucketTotal,
                                                      const unsigned* __restrict__ bucketStart,
                                                      unsigned* __restrict__ sorted) {
    __shared__ unsigned s_cur[K_BUCKETS];
    __shared__ int      s_base[K_BUCKETS];
    __shared__ unsigned ssum[256];
    __shared__ unsigned ent[CHUNK];
    __shared__ unsigned short bk[CHUNK];

    int t = threadIdx.x;
    int k = blockIdx.x;
    int base = k * CHUNK;
    const unsigned* row  = blockHist + (size_t)k * K_BUCKETS;
    const unsigned* rowN = blockHist + (size_t)(k + 1) * K_BUCKETS;
    bool last = (k == SORT_BLOCKS - 1);

    unsigned v[4], g0[4], run = 0;
#pragma unroll
    for (int j = 0; j < 4; j++) {
        int idx = 4 * t + j;
        if (idx < K_BUCKETS) {
            unsigned r0 = row[idx];
            unsigned r1 = last ? bucketTotal[idx] : rowN[idx];
            g0[j] = r0;
            v[j]  = r1 - r0;
        } else { g0[j] = 0; v[j] = 0; }
    }
#pragma unroll
    for (int j = 0; j < 4; j++) { unsigned tmp = v[j]; v[j] = run; run += tmp; }
    ssum[t] = run;
    __syncthreads();
    for (int off = 1; off < 256; off <<= 1) {
        unsigned add = (t >= off) ? ssum[t - off] : 0u;
        __syncthreads();
        ssum[t] += add;
        __syncthreads();
    }
    unsigned excl = ssum[t] - run;
#pragma unroll
    for (int j = 0; j < 4; j++) {
        int idx = 4 * t + j;
        if (idx < K_BUCKETS) {
            unsigned st = excl + v[j];
            s_cur[idx]  = st;
            s_base[idx] = (int)(bucketStart[idx] + g0[j]) - (int)st;
        }
    }
    __syncthreads();

    for (int e = base + t; e < base + CHUNK; e += 256) {
        unsigned d = (unsigned)dst[e];
        unsigned s = (unsigned)src[e];
        unsigned b = d >> RANGE_SHIFT;
        unsigned lpos = atomicAdd(&s_cur[b], 1u);
        ent[lpos] = s | ((d & 255u) << 18);
        bk[lpos] = (unsigned short)b;
    }
    __syncthreads();

    for (int i = t; i < CHUNK; i += 256) {
        unsigned b = bk[i];
        sorted[s_base[b] + i] = ent[i];
    }
}

// ---------------- sort phase B v2 + fused node1w ----------------
// One block per bucket. Pass 1: hist only (no staging). Pass 2: re-read
// (L2-hot) and place into LDS ent2 at sorted position (divergent LDS write),
// then COALESCED global write-out -- replaces R13's scattered global write.
// Thread t owns node b*256+t: emits nodeStart, dinv, u (node1w fused).
// In-place safe: all reads of the bucket complete before any write-back.
__global__ __launch_bounds__(256) void sortbins_kernel(unsigned* __restrict__ sorted,
                                                       const unsigned* __restrict__ bucketStart,
                                                       unsigned* __restrict__ nodeStart,
                                                       const float2* __restrict__ x,
                                                       float* __restrict__ dinv,
                                                       float2* __restrict__ u) {
    __shared__ unsigned ent2[CAPB];
    __shared__ unsigned hist[256];
    __shared__ unsigned cur[256];
    __shared__ unsigned ssum[256];
    int t = threadIdx.x, b = blockIdx.x;
    int base = (int)bucketStart[b];
    int n = (int)bucketStart[b + 1] - base;
    if (n > CAPB) return;  // block-uniform; astronomically improbable

    hist[t] = 0;
    __syncthreads();
    // pass 1: histogram only
    for (int i = t; i < n; i += 256)
        atomicAdd(&hist[(sorted[base + i] >> 18) & 255u], 1u);
    __syncthreads();
    unsigned v = hist[t];
    ssum[t] = v;
    __syncthreads();
    for (int off = 1; off < 256; off <<= 1) {
        unsigned add = (t >= off) ? ssum[t - off] : 0u;
        __syncthreads();
        ssum[t] += add;
        __syncthreads();
    }
    unsigned excl = ssum[t] - v;
    cur[t] = excl;
    int node = (b << RANGE_SHIFT) + t;
    if (node < N_NODES) {
        nodeStart[node] = (unsigned)(base + (int)excl);
        float di = rsqrtf((float)(v + 1u));   // +1 self loop (fused node1w)
        dinv[node] = di;
        float2 xi = x[node];
        u[node] = make_float2(di * xi.x, di * xi.y);
    }
    if (b == K_BUCKETS - 1 && t == 0) nodeStart[N_NODES] = bucketStart[K_BUCKETS];
    __syncthreads();
    // pass 2: re-read (L2-hot) and place into LDS at sorted position
    for (int i = t; i < n; i += 256) {
        unsigned w = sorted[base + i];
        unsigned p = atomicAdd(&cur[(w >> 18) & 255u], 1u);
        ent2[p] = w;
    }
    __syncthreads();
    // coalesced write-out
    for (int i = t; i < n; i += 256) sorted[base + i] = ent2[i];
}

// ---------------- GCN phase (verbatim R13) ----------------

// Layer 1: one wave per node. Coalesced run read, divergent gather ONLY,
// register accumulate, butterfly reduce, fused 2->16->2 MLP epilogue.
__global__ __launch_bounds__(256) void aggw1_kernel(const unsigned* __restrict__ sorted,
                                                    const unsigned* __restrict__ nodeStart,
                                                    const float2* __restrict__ u,
                                                    const float* __restrict__ dinv,
                                                    const float* __restrict__ W1,
                                                    const float* __restrict__ b1,
                                                    const float* __restrict__ W2,
                                                    float2* __restrict__ g2) {
    int i = blockIdx.x * 4 + (threadIdx.x >> 6);
    if (i >= N_NODES) return;
    int lane = threadIdx.x & 63;
    int e0 = (int)nodeStart[i], e1 = (int)nodeStart[i + 1];
    float ax = 0.f, ay = 0.f;
    for (int k = e0 + lane; k < e1; k += 64) {
        unsigned w = sorted[k];
        float2 v = u[w & 0x3FFFFu];
        ax += v.x; ay += v.y;
    }
#pragma unroll
    for (int off = 32; off; off >>= 1) {
        ax += __shfl_xor(ax, off);
        ay += __shfl_xor(ay, off);
    }
    float di = dinv[i];
    float2 uu = u[i];
    float c0 = di * (ax + uu.x);
    float c1 = di * (ay + uu.y);
    float a0 = 0.f, a1 = 0.f;
    if (lane < 16) {
        float o = fmaxf(c0 * W1[lane] + c1 * W1[16 + lane] + b1[lane], 0.f);  // W1 (2,16)
        a0 = o * W2[2 * lane];                                                // W2 (16,2)
        a1 = o * W2[2 * lane + 1];
    }
#pragma unroll
    for (int off = 8; off; off >>= 1) {
        a0 += __shfl_xor(a0, off);
        a1 += __shfl_xor(a1, off);
    }
    if (lane == 0) g2[i] = make_float2(di * a0, di * a1);
}

// Layer 2: same core over table=g2; bias epilogue.
__global__ __launch_bounds__(256) void aggw2_kernel(const unsigned* __restrict__ sorted,
                                                    const unsigned* __restrict__ nodeStart,
                                                    const float2* __restrict__ g2,
                                                    const float* __restrict__ dinv,
                                                    const float* __restrict__ b2,
                                                    float2* __restrict__ out) {
    int i = blockIdx.x * 4 + (threadIdx.x >> 6);
    if (i >= N_NODES) return;
    int lane = threadIdx.x & 63;
    int e0 = (int)nodeStart[i], e1 = (int)nodeStart[i + 1];
    float ax = 0.f, ay = 0.f;
    for (int k = e0 + lane; k < e1; k += 64) {
        unsigned w = sorted[k];
        float2 v = g2[w & 0x3FFFFu];
        ax += v.x; ay += v.y;
    }
#pragma unroll
    for (int off = 32; off; off >>= 1) {
        ax += __shfl_xor(ax, off);
        ay += __shfl_xor(ay, off);
    }
    if (lane == 0) {
        float di = dinv[i];
        float2 g = g2[i];
        out[i] = make_float2(di * (ax + g.x) + b2[0],
                             di * (ay + g.y) + b2[1]);
    }
}

// ---------------- fallback path (R2-style, needs only 8 MB ws) ----------------

__global__ __launch_bounds__(256) void fb_deg(const int* __restrict__ dst, int* __restrict__ degi) {
    int e = blockIdx.x * 256 + threadIdx.x;
    if (e < N_EDGES) atomicAdd(&degi[dst[e]], 1);
}
__global__ __launch_bounds__(256) void fb_node1(const float* __restrict__ x, const int* __restrict__ degi,
                                                float* __restrict__ dinv, float2* __restrict__ u) {
    int i = blockIdx.x * 256 + threadIdx.x;
    if (i >= N_NODES) return;
    float di = rsqrtf((float)(degi[i] + 1));
    dinv[i] = di;
    float2 xi = ((const float2*)x)[i];
    u[i] = make_float2(di * xi.x, di * xi.y);
}
__global__ __launch_bounds__(256) void fb_agg(const int* __restrict__ src, const int* __restrict__ dst,
                                              const float2* __restrict__ table, float* __restrict__ acc) {
    int e = blockIdx.x * 256 + threadIdx.x;
    if (e >= N_EDGES) return;
    float2 v = table[src[e]];
    size_t d = dst[e];
    unsafeAtomicAdd(&acc[2 * d], v.x);
    unsafeAtomicAdd(&acc[2 * d + 1], v.y);
}
__global__ __launch_bounds__(256) void fb_node2(const float2* __restrict__ u, const float2* __restrict__ A1,
                                                const float* __restrict__ W1, const float* __restrict__ b1,
                                                const float* __restrict__ W2, const float* __restrict__ dinv,
                                                float2* __restrict__ g2) {
    int i = blockIdx.x * 256 + threadIdx.x;
    if (i >= N_NODES) return;
    float di = dinv[i];
    float2 a = A1[i], uu = u[i];
    float c0 = di * (a.x + uu.x), c1 = di * (a.y + uu.y);
    float a0 = 0.f, a1 = 0.f;
#pragma unroll
    for (int f = 0; f < 16; f++) {
        float o = fmaxf(c0 * W1[f] + c1 * W1[16 + f] + b1[f], 0.f);
        a0 += o * W2[2 * f];
        a1 += o * W2[2 * f + 1];
    }
    g2[i] = make_float2(di * a0, di * a1);
}
__global__ __launch_bounds__(256) void fb_node3(const float2* __restrict__ g2, const float2* __restrict__ A2,
                                                const float* __restrict__ b2, const float* __restrict__ dinv,
                                                float2* __restrict__ out) {
    int i = blockIdx.x * 256 + threadIdx.x;
    if (i >= N_NODES) return;
    float di = dinv[i];
    float2 a = A2[i], g = g2[i];
    out[i] = make_float2(di * (a.x + g.x) + b2[0], di * (a.y + g.y) + b2[1]);
}

// ---------------- launcher ----------------

extern "C" void kernel_launch(void* const* d_in, const int* in_sizes, int n_in,
                              void* d_out, int out_size, void* d_ws, size_t ws_size,
                              hipStream_t stream) {
    const float* x  = (const float*)d_in[0];
    const float* W1 = (const float*)d_in[1];
    const float* b1 = (const float*)d_in[2];
    const float* W2 = (const float*)d_in[3];
    const float* b2 = (const float*)d_in[4];
    const int* ei   = (const int*)d_in[5];   // (2,E): row 0 = src, row 1 = dst
    const int* src = ei;
    const int* dst = ei + N_EDGES;
    float2* out = (float2*)d_out;

    // ws layout (4B words), identical total to R13's proven 57.7 MB:
    //   sorted [E]                           12,800,000
    //   region [1,601,536]  -- blockHist (2048*782) during sort; after
    //       scatter: nodeStart [0..200,004) + dinv [..400,004) +
    //       u [..800,004) + g2 [..1,200,004)   (fits)
    //   bucketTotal [782] ; bucketStart [783+pad]
    const size_t need = ((size_t)N_EDGES + (size_t)SORT_BLOCKS * K_BUCKETS + 782 + 784) * 4;

    if (ws_size >= need) {
        unsigned* sorted      = (unsigned*)d_ws;
        unsigned* region      = sorted + N_EDGES;
        unsigned* blockHist   = region;
        unsigned* nodeStart   = region;                       // overlay (post-scatter)
        float*    dinv        = (float*)(region + 200004);
        float2*   u           = (float2*)(region + 400004);
        float2*   g2          = (float2*)(region + 800004);
        unsigned* bucketTotal = region + (size_t)SORT_BLOCKS * K_BUCKETS;
        unsigned* bucketStart = bucketTotal + 782;

        hist_kernel<<<SORT_BLOCKS, 256, 0, stream>>>(dst, blockHist);
        scan_perblock_kernel<<<K_BUCKETS, 256, 0, stream>>>(blockHist, bucketTotal);
        scan_buckets_kernel<<<1, 1024, 0, stream>>>(bucketTotal, bucketStart);
        scatter_kernel<<<SORT_BLOCKS, 256, 0, stream>>>(src, dst, blockHist, bucketTotal,
                                                        bucketStart, sorted);
        sortbins_kernel<<<K_BUCKETS, 256, 0, stream>>>(sorted, bucketStart, nodeStart,
                                                       (const float2*)x, dinv, u);
        aggw1_kernel<<<(N_NODES + 3) / 4, 256, 0, stream>>>(sorted, nodeStart, u, dinv,
                                                            W1, b1, W2, g2);
        aggw2_kernel<<<(N_NODES + 3) / 4, 256, 0, stream>>>(sorted, nodeStart, g2, dinv,
                                                            b2, out);
    } else {
        // R2-style fallback (8 MB ws): global atomics, ~3.1 ms.
        float* ws = (float*)d_ws;
        int*   degi = (int*)ws;
        float* A1   = ws + N_NODES;
        float* A2   = A1 + 2 * (size_t)N_NODES;
        float* dinvF = A2 + 2 * (size_t)N_NODES;
        float2* uF  = (float2*)(dinvF + N_NODES);
        float2* g2F = uF + N_NODES;
        constexpr int EB = (N_EDGES + 255) / 256;
        constexpr int NB = (N_NODES + 255) / 256;
        (void)hipMemsetAsync(degi, 0, 5 * (size_t)N_NODES * sizeof(float), stream);
        fb_deg<<<EB, 256, 0, stream>>>(dst, degi);
        fb_node1<<<NB, 256, 0, stream>>>(x, degi, dinvF, uF);
        fb_agg<<<EB, 256, 0, stream>>>(src, dst, uF, A1);
        fb_node2<<<NB, 256, 0, stream>>>(uF, (const float2*)A1, W1, b1, W2, dinvF, g2F);
        fb_agg<<<EB, 256, 0, stream>>>(src, dst, g2F, A2);
        fb_node3<<<NB, 256, 0, stream>>>(g2F, (const float2*)A2, b2, dinvF, out);
    }
}